// Round 6
// baseline (406.699 us; speedup 1.0000x reference)
//
#include <hip/hip_runtime.h>
#include <hip/hip_fp16.h>
#include <math.h>

#define DIM      32
#define HDIM     16                // DIM/2 float2 pairs per row
#define N_NODES  100000
#define N_EDGES  1600000
#define L0       0.1f

// ---- u-binning parameters (R6: occupancy-fixed geometry) ----
#define NBK      1024              // u-buckets
#define NPB      98                // nodes per bucket (1024*98 = 100,352)
#define CAP      2240              // records/bucket (mean 1568, +17 sigma)
#define TILE     2048              // edges per bin tile
#define NT       ((N_EDGES + TILE - 1) / TILE)   // 782 tiles

// ===========================================================================
// R5 post-mortem: dataflow was right (atomic WRITE halved to 112MB, FETCH
// halved to 82MB) but the launch geometry starved it: 511 x 1024-thr blocks
// = 8176 waves vs 8192 capacity -> 45% measured occupancy, no latency
// hiding.  R6 keeps the dataflow, fixes geometry: 1024 buckets x 98 nodes,
// 512-thr blocks (4 blk/CU, 32 waves/CU), 12.5KB slice, one memset, no out
// memset (slices cover grad fully), 3 dispatches total.
// ===========================================================================

// ---- Phase 1: tile-local counting sort of edges by u-bucket (1024 bkts) ----
__global__ __launch_bounds__(512) void bin_u_kernel(
    const int*    __restrict__ edges,
    unsigned int* __restrict__ gcursor,   // NBK counters (ws, zeroed)
    unsigned int* __restrict__ recs_g)    // NBK*CAP u32 records (ws)
{
    __shared__ unsigned int   recs[TILE];   // 8 KB
    __shared__ unsigned int   srec[TILE];   // 8 KB
    __shared__ unsigned short rb  [TILE];   // 4 KB
    __shared__ unsigned short srb [TILE];   // 4 KB
    __shared__ unsigned int   hist [NBK];   // 4 KB
    __shared__ unsigned int   excl [NBK];   // 4 KB
    __shared__ unsigned int   gbase[NBK];   // 4 KB
    __shared__ unsigned int   cnt  [NBK];   // 4 KB
    __shared__ unsigned int   pscan[512];   // 2 KB

    const int t    = threadIdx.x;
    const int base = blockIdx.x * TILE;
    const int nrec = min(TILE, N_EDGES - base);

    #pragma unroll
    for (int j = t; j < NBK; j += 512) { hist[j] = 0; cnt[j] = 0; }
    __syncthreads();

    // build records (dl 7b | v 17b) and histogram
    #pragma unroll
    for (int i = 0; i < TILE / 512; ++i) {
        const int e = base + i * 512 + t;
        if (e < N_EDGES) {
            const int2 ev = ((const int2*)edges)[e];
            const int bu = ev.x / NPB;
            const int du = ev.x - bu * NPB;
            recs[i * 512 + t] = (unsigned)du | ((unsigned)ev.y << 7);
            rb[i * 512 + t]   = (unsigned short)bu;
            atomicAdd(&hist[bu], 1u);
        }
    }
    __syncthreads();

    // scan 1024 buckets: pair-sum -> 512-wide Hillis-Steele -> expand
    const unsigned h0 = hist[2 * t];
    const unsigned h1 = hist[2 * t + 1];
    const unsigned pp = h0 + h1;
    pscan[t] = pp;
    __syncthreads();
    for (int off = 1; off < 512; off <<= 1) {
        const unsigned add = (t >= off) ? pscan[t - off] : 0u;
        __syncthreads();
        pscan[t] += add;
        __syncthreads();
    }
    const unsigned pairExcl = pscan[t] - pp;
    excl[2 * t]     = pairExcl;
    excl[2 * t + 1] = pairExcl + h0;
    gbase[2 * t]     = h0 ? atomicAdd(&gcursor[2 * t], h0) : 0u;
    gbase[2 * t + 1] = h1 ? atomicAdd(&gcursor[2 * t + 1], h1) : 0u;
    __syncthreads();

    // scatter into sorted LDS order
    for (int r = t; r < nrec; r += 512) {
        const unsigned short b  = rb[r];
        const unsigned int   lo = atomicAdd(&cnt[b], 1u);
        const unsigned int   pos = excl[b] + lo;
        srec[pos] = recs[r];
        srb[pos]  = b;
    }
    __syncthreads();

    // coalesced write-out of per-bucket runs
    for (int j = t; j < nrec; j += 512) {
        const unsigned short b   = srb[j];
        const unsigned int   idx = gbase[b] + ((unsigned)j - excl[b]);
        if (idx < CAP)                         // defensive (+17 sigma margin)
            recs_g[(unsigned)b * CAP + idx] = srec[j];
    }
}

// ---- Phase 2: one 512-thr block per u-bucket.  u-grad in 12.5KB LDS slice;
//      v-grad via R0's f16-packed atomics; 4 records/quad in flight. ----
__global__ __launch_bounds__(512) void bucket_kernel(
    const float*        __restrict__ x,
    const unsigned int* __restrict__ recs_g,
    const unsigned int* __restrict__ gcursor,
    __half2*            __restrict__ grad_h,  // N_NODES*HDIM (ws, zeroed)
    float*              __restrict__ energy_ws,  // 1 float (ws, zeroed)
    float*              __restrict__ out)
{
    __shared__ float  lg[NPB * DIM];          // 12,544 B u-grad slice
    __shared__ double s_e[8];

    const int b     = blockIdx.x;
    const int t     = threadIdx.x;
    const int lane  = t & 63;
    const int k     = lane & 15;              // float2 pair index
    const int qId   = (t >> 6) * 4 + (lane >> 4);   // quad id 0..31
    const int node0 = b * NPB;
    const int nnode = min(NPB, N_NODES - node0);    // <=0 for trailing bkts

    for (int j = t; j < NPB * DIM; j += 512) lg[j] = 0.0f;
    __syncthreads();

    const int nrec = min((int)gcursor[b], CAP);
    const float2* __restrict__ x2 = (const float2*)x;
    const float Jx = (k == 0) ? -1.0f : 1.0f;
    const int qBase = b * CAP;

    double energy = 0.0;

    for (int i = 4 * qId; i < nrec; i += 128) {
        const int rem = nrec - i;             // >= 1
        uint4 rr;
        if (rem >= 4) {
            rr = *reinterpret_cast<const uint4*>(recs_g + qBase + i);
        } else {
            rr.x = recs_g[qBase + i];
            rr.y = (rem > 1) ? recs_g[qBase + i + 1] : 0u;
            rr.z = (rem > 2) ? recs_g[qBase + i + 2] : 0u;
            rr.w = 0u;
        }
        const int n = min(rem, 4);
        const unsigned int rec[4] = {rr.x, rr.y, rr.z, rr.w};

        int dl[4], v[4];
        float2 xu[4], xv[4];
        #pragma unroll
        for (int r = 0; r < 4; ++r) {
            dl[r] = (int)(rec[r] & 127u);
            v[r]  = (int)(rec[r] >> 7);
            xu[r] = x2[(node0 + dl[r]) * HDIM + k];   // warm (slice rows)
            xv[r] = x2[v[r] * HDIM + k];              // cold gather
        }

        float p[4];
        #pragma unroll
        for (int r = 0; r < 4; ++r)
            p[r] = Jx * xu[r].x * xv[r].x + xu[r].y * xv[r].y;
        #pragma unroll
        for (int off = 8; off; off >>= 1) {
            #pragma unroll
            for (int r = 0; r < 4; ++r)
                p[r] += __shfl_xor(p[r], off, 16);
        }

        #pragma unroll
        for (int r = 0; r < 4; ++r) {
            if (r < n) {
                const float inner = fminf(p[r], -1.0000001f);
                const float zm1   = -inner - 1.0f;
                const float s     = sqrtf(zm1 * (zm1 + 2.0f));
                const float dist  = log1pf(zm1 + s);
                const float delta = dist - L0;
                const float f     = -delta / (s + 1e-9f);
                // v-side: R0's proven f16-packed atomic pipe (half volume)
                unsafeAtomicAdd(&grad_h[v[r] * HDIM + k],
                                __floats2half2_rn(f * Jx * xu[r].x,
                                                  f * xu[r].y));
                // u-side: f32 LDS slice, written once at the end
                atomicAdd(&lg[dl[r] * DIM + 2 * k],     f * Jx * xv[r].x);
                atomicAdd(&lg[dl[r] * DIM + 2 * k + 1], f * xv[r].y);
                if (k == 0)
                    energy += 0.5 * (double)delta * (double)delta;
            }
        }
    }

    // energy reduce: wave butterfly -> block -> one ws atomic
    #pragma unroll
    for (int off = 32; off; off >>= 1)
        energy += __shfl_xor(energy, off, 64);
    if (lane == 0) s_e[t >> 6] = energy;
    __syncthreads();                 // also orders LDS atomics before writeout
    if (t == 0) {
        double tot = 0.0;
        #pragma unroll
        for (int w = 0; w < 8; ++w) tot += s_e[w];
        atomicAdd(energy_ws, (float)tot);
    }

    // exclusive slice -> plain coalesced stores (covers ALL grad elements
    // across blocks -> no out memset anywhere)
    if (nnode > 0) {
        float* __restrict__ grad = out + 1;
        const int lim = nnode * DIM;
        for (int j = t; j < lim; j += 512)
            grad[node0 * DIM + j] = lg[j];
    }
}

// ---- Phase 3: add f16 v-side into out, publish energy ----
__global__ __launch_bounds__(256) void combine_kernel(
    const __half2* __restrict__ grad_h,
    const float*   __restrict__ energy_ws,
    float*         __restrict__ out)
{
    const int i = blockIdx.x * 256 + threadIdx.x;     // over N_NODES*HDIM
    if (i < N_NODES * HDIM) {
        const float2 f = __half22float2(grad_h[i]);
        out[1 + 2 * i]     += f.x;
        out[1 + 2 * i + 1] += f.y;
    }
    if (i == 0) out[0] = *energy_ws;
}

// ===========================================================================
// Fallback 1 (ws >= 6.4MB): round-0 f16-packed-atomic kernel, 266 us.
// ===========================================================================
__global__ __launch_bounds__(256) void spring_edge_f16_kernel(
    const float*  __restrict__ x,
    const int*    __restrict__ edges,
    __half2*      __restrict__ grad_h,
    float*        __restrict__ energy_ws)
{
    const int tid   = threadIdx.x;
    const int lane  = tid & 63;
    const int k     = lane & 15;
    const int quad  = lane >> 4;
    const int qId   = ((blockIdx.x * blockDim.x + tid) >> 6) * 4 + quad;
    const int nQuad = ((gridDim.x * blockDim.x) >> 6) * 4;

    const float2* __restrict__ x2 = (const float2*)x;
    const float Jx = (k == 0) ? -1.0f : 1.0f;

    double energy = 0.0;

    for (int e0 = qId; e0 < N_EDGES; e0 += 2 * nQuad) {
        const int  e1 = e0 + nQuad;
        const bool a1 = (e1 < N_EDGES);

        const int2 ev0 = ((const int2*)edges)[e0];
        const int2 ev1 = a1 ? ((const int2*)edges)[e1] : make_int2(0, 0);
        const float2 xu0 = x2[ev0.x * HDIM + k];
        const float2 xv0 = x2[ev0.y * HDIM + k];
        const float2 xu1 = x2[ev1.x * HDIM + k];
        const float2 xv1 = x2[ev1.y * HDIM + k];

        float p0 = Jx * xu0.x * xv0.x + xu0.y * xv0.y;
        float p1 = Jx * xu1.x * xv1.x + xu1.y * xv1.y;
        #pragma unroll
        for (int off = 8; off; off >>= 1) {
            p0 += __shfl_xor(p0, off, 16);
            p1 += __shfl_xor(p1, off, 16);
        }

        {
            const float inner = fminf(p0, -1.0000001f);
            const float zm1   = -inner - 1.0f;
            const float s     = sqrtf(zm1 * (zm1 + 2.0f));
            const float dist  = log1pf(zm1 + s);
            const float delta = dist - L0;
            const float f     = -delta / (s + 1e-9f);
            unsafeAtomicAdd(&grad_h[ev0.x * HDIM + k],
                            __floats2half2_rn(f * Jx * xv0.x, f * xv0.y));
            unsafeAtomicAdd(&grad_h[ev0.y * HDIM + k],
                            __floats2half2_rn(f * Jx * xu0.x, f * xu0.y));
            if (k == 0) energy += 0.5 * (double)delta * (double)delta;
        }
        if (a1) {
            const float inner = fminf(p1, -1.0000001f);
            const float zm1   = -inner - 1.0f;
            const float s     = sqrtf(zm1 * (zm1 + 2.0f));
            const float dist  = log1pf(zm1 + s);
            const float delta = dist - L0;
            const float f     = -delta / (s + 1e-9f);
            unsafeAtomicAdd(&grad_h[ev1.x * HDIM + k],
                            __floats2half2_rn(f * Jx * xv1.x, f * xv1.y));
            unsafeAtomicAdd(&grad_h[ev1.y * HDIM + k],
                            __floats2half2_rn(f * Jx * xu1.x, f * xu1.y));
            if (k == 0) energy += 0.5 * (double)delta * (double)delta;
        }
    }

    #pragma unroll
    for (int off = 32; off; off >>= 1)
        energy += __shfl_xor(energy, off, 64);

    __shared__ double s_e[4];
    if (lane == 0) s_e[tid >> 6] = energy;
    __syncthreads();
    if (tid == 0)
        atomicAdd(energy_ws, (float)(s_e[0] + s_e[1] + s_e[2] + s_e[3]));
}

__global__ __launch_bounds__(256) void convert_kernel(
    const __half2* __restrict__ grad_h,
    const float*   __restrict__ energy_ws,
    float*         __restrict__ out)
{
    const int i = blockIdx.x * 256 + threadIdx.x;
    if (i < N_NODES * HDIM) {
        const float2 f = __half22float2(grad_h[i]);
        out[1 + 2 * i]     = f.x;
        out[1 + 2 * i + 1] = f.y;
    }
    if (i == 0) out[0] = *energy_ws;
}

// ===========================================================================
// Fallback 2 (no usable ws): known-correct fused kernel.
// ===========================================================================
__global__ __launch_bounds__(256) void spring_edge_kernel(
    const float* __restrict__ x,
    const int*   __restrict__ edges,
    float*       __restrict__ out)
{
    const int tid    = threadIdx.x;
    const int lane   = tid & 63;
    const int d      = lane & 31;
    const int half   = lane >> 5;
    const int waveId = (blockIdx.x * blockDim.x + tid) >> 6;
    const int nWaves = (gridDim.x * blockDim.x) >> 6;

    float* __restrict__ grad = out + 1;
    const float Jd = (d == 0) ? -1.0f : 1.0f;
    double energy = 0.0;

    for (int e0 = waveId * 2; e0 < N_EDGES; e0 += nWaves * 2) {
        const int  e      = e0 + half;
        const bool active = (e < N_EDGES);
        int u = 0, v = 0;
        float xu = 0.0f, xv = 0.0f;
        if (active) {
            u  = edges[2 * e];
            v  = edges[2 * e + 1];
            xu = x[u * DIM + d];
            xv = x[v * DIM + d];
        }
        float p = xu * xv;
        if (d == 0) p = -p;
        #pragma unroll
        for (int off = 16; off; off >>= 1)
            p += __shfl_xor(p, off, 32);

        const float inner  = fminf(p, -1.0000001f);
        const float zm1    = -inner - 1.0f;
        const float s      = sqrtf(zm1 * (zm1 + 2.0f));
        const float dist   = log1pf(zm1 + s);
        const float delta  = dist - L0;
        const float factor = -delta / (s + 1e-9f);

        if (active) {
            atomicAdd(&grad[u * DIM + d], factor * xv * Jd);
            atomicAdd(&grad[v * DIM + d], factor * xu * Jd);
            if (d == 0)
                energy += 0.5 * (double)delta * (double)delta;
        }
    }
    #pragma unroll
    for (int off = 32; off; off >>= 1)
        energy += __shfl_xor(energy, off, 64);
    __shared__ double s_e[4];
    if (lane == 0) s_e[tid >> 6] = energy;
    __syncthreads();
    if (tid == 0)
        atomicAdd(&out[0], (float)(s_e[0] + s_e[1] + s_e[2] + s_e[3]));
}

extern "C" void kernel_launch(void* const* d_in, const int* in_sizes, int n_in,
                              void* d_out, int out_size, void* d_ws, size_t ws_size,
                              hipStream_t stream) {
    const float* x     = (const float*)d_in[0];
    const int*   edges = (const int*)d_in[1];
    float*       out   = (float*)d_out;

    // ---- R6 workspace layout: [gcursor 4KB][energy 4B pad][grad_h 6.4MB]
    //      [recs 9.18MB]; one memset covers everything that needs zeroing.
    const size_t cur_bytes  = (size_t)NBK * sizeof(unsigned int);        // 4 KB
    const size_t en_off     = cur_bytes;                                 // 4096
    const size_t gh_off     = 8192;
    const size_t gh_bytes   = (size_t)N_NODES * HDIM * sizeof(__half2);  // 6.4 MB
    const size_t zero_bytes = gh_off + gh_bytes;
    const size_t rec_off    = zero_bytes;                                // 16-aligned
    const size_t rec_bytes  = (size_t)NBK * CAP * sizeof(unsigned int);  // 9.18 MB
    const size_t r6_need    = rec_off + rec_bytes;                       // ~15.6 MB

    const size_t f16_need   = gh_bytes + sizeof(float);

    if (ws_size >= r6_need) {
        unsigned int* gcursor   = (unsigned int*)d_ws;
        float*        energy_ws = (float*)((char*)d_ws + en_off);
        __half2*      grad_h    = (__half2*)((char*)d_ws + gh_off);
        unsigned int* recs_g    = (unsigned int*)((char*)d_ws + rec_off);

        hipMemsetAsync(d_ws, 0, zero_bytes, stream);
        bin_u_kernel<<<NT, 512, 0, stream>>>(edges, gcursor, recs_g);
        bucket_kernel<<<NBK, 512, 0, stream>>>(x, recs_g, gcursor,
                                               grad_h, energy_ws, out);
        combine_kernel<<<(N_NODES * HDIM + 255) / 256, 256, 0, stream>>>(
            grad_h, energy_ws, out);
    } else if (ws_size >= f16_need) {
        __half2* grad_h    = (__half2*)d_ws;
        float*   energy_ws = (float*)((char*)d_ws + gh_bytes);

        hipMemsetAsync(d_ws, 0, f16_need, stream);
        spring_edge_f16_kernel<<<4096, 256, 0, stream>>>(x, edges, grad_h,
                                                         energy_ws);
        convert_kernel<<<(N_NODES * HDIM + 255) / 256, 256, 0, stream>>>(
            grad_h, energy_ws, out);
    } else {
        hipMemsetAsync(out, 0, (size_t)out_size * sizeof(float), stream);
        spring_edge_kernel<<<4096, 256, 0, stream>>>(x, edges, out);
    }
}